// Round 1
// baseline (17.385 us; speedup 1.0000x reference)
//
#include <hip/hip_runtime.h>

#define RES 128           // grid resolution
#define NPT (RES * RES)   // 16384 points per (b,t)

// One block per (b,t). 256 threads; each thread owns 4 consecutive grid
// columns (fixed dx) and 16 of the 128 rows -> 64 points in registers.
__global__ __launch_bounds__(256) void AnalyticalDecoder_85581518340204_kernel(
    const float* __restrict__ mu,
    const float* __restrict__ covar,
    float* __restrict__ out)
{
    const int bt  = blockIdx.x;   // b*T + t, 0..1023
    const int tid = threadIdx.x;  // 0..255

    // Broadcast per-(b,t) params (same for all threads -> scalar loads)
    const float mux = mu[bt * 2 + 0];
    const float muy = mu[bt * 2 + 1];
    const float a = covar[bt * 4 + 0];
    const float b = covar[bt * 4 + 1];
    const float c = covar[bt * 4 + 2];
    const float d = covar[bt * 4 + 3];
    const float det     = a * d - b * c;
    const float inv_det = 1.0f / det;

    const float step = 30.0f / 127.0f;  // linspace(-15,15,128) spacing

    // This thread's 4 consecutive columns: j = (tid&31)*4 + e
    // q(dx,dy) = inv_det*(d*dx^2 - (b+c)*dx*dy + a*dy^2)
    //          = A0[e] + dy*(A1[e] + A2*dy)
    const int j0 = (tid & 31) * 4;
    float A0[4], A1[4];
    const float A2 = a * inv_det;
    #pragma unroll
    for (int e = 0; e < 4; ++e) {
        const float px = -15.0f + (float)(j0 + e) * step;
        const float dx = px - mux;
        A0[e] = d * dx * dx * inv_det;
        A1[e] = -(b + c) * dx * inv_det;
    }

    // Rows: i = it*8 + (tid>>5), it = 0..15  (covers 0..127)
    const int i0 = tid >> 5;
    float p[16][4];
    float mn = 3.4e38f, mx = -3.4e38f;
    #pragma unroll
    for (int it = 0; it < 16; ++it) {
        const int   i  = it * 8 + i0;
        const float py = -15.0f + (float)i * step;
        const float dy = py - muy;
        const float t1 = A2 * dy;
        #pragma unroll
        for (int e = 0; e < 4; ++e) {
            const float q = A0[e] + dy * (A1[e] + t1);
            // normalization cancels the 1/(2*pi*sqrt(det)) factor
            const float v = __expf(-0.5f * q);
            p[it][e] = v;
            mn = fminf(mn, v);
            mx = fmaxf(mx, v);
        }
    }

    // Wave64 butterfly reduction for min/max
    #pragma unroll
    for (int off = 32; off > 0; off >>= 1) {
        mn = fminf(mn, __shfl_xor(mn, off));
        mx = fmaxf(mx, __shfl_xor(mx, off));
    }
    // Combine the block's 4 waves via LDS
    __shared__ float smn[4], smx[4];
    const int wave = tid >> 6;
    if ((tid & 63) == 0) { smn[wave] = mn; smx[wave] = mx; }
    __syncthreads();
    mn = fminf(fminf(smn[0], smn[1]), fminf(smn[2], smn[3]));
    mx = fmaxf(fmaxf(smx[0], smx[1]), fmaxf(smx[2], smx[3]));

    const float inv = 1.0f / (mx - mn);

    // Coalesced float4 stores: float4 index = it*256 + tid
    float4* out4 = (float4*)(out + (size_t)bt * NPT);
    #pragma unroll
    for (int it = 0; it < 16; ++it) {
        float4 v;
        v.x = (p[it][0] - mn) * inv;
        v.y = (p[it][1] - mn) * inv;
        v.z = (p[it][2] - mn) * inv;
        v.w = (p[it][3] - mn) * inv;
        out4[it * 256 + tid] = v;
    }
}

extern "C" void kernel_launch(void* const* d_in, const int* in_sizes, int n_in,
                              void* d_out, int out_size, void* d_ws, size_t ws_size,
                              hipStream_t stream) {
    const float* mu    = (const float*)d_in[0];   // [BS,T,2]
    const float* covar = (const float*)d_in[1];   // [BS,T,2,2]
    float* out = (float*)d_out;                   // [BS,T,1,RES,RES] f32
    const int n_bt = in_sizes[0] / 2;             // BS*T = 1024
    AnalyticalDecoder_85581518340204_kernel<<<n_bt, 256, 0, stream>>>(mu, covar, out);
}